// Round 8
// baseline (1823.584 us; speedup 1.0000x reference)
//
#include <hip/hip_runtime.h>
#include <float.h>

#define NQ 8
#define NB 8
#define ND 128
#define NT 8192
#define NK 1024
#define TTILE 64
#define KCHUNK 256
#define DCHUNK 32
#define EBS 260   // eb row stride in floats (pad for bank spread + 16B align)

// numpy pairwise-8 sum of squares over 128 values (np.sum(a*a, -1) for n=128):
// products rounded individually, 8 stride-8 accumulators, fixed combine tree.
__device__ __forceinline__ float np_sumsq_strided(const float* __restrict__ a, int stride) {
#pragma clang fp contract(off)
    float r[8];
    #pragma unroll
    for (int j = 0; j < 8; ++j) { float v = a[j * stride]; r[j] = v * v; }
    #pragma unroll
    for (int i = 1; i < 16; ++i) {
        #pragma unroll
        for (int j = 0; j < 8; ++j) {
            float v = a[(i * 8 + j) * stride];
            r[j] = r[j] + v * v;
        }
    }
    return ((r[0] + r[1]) + (r[2] + r[3])) + ((r[4] + r[5]) + (r[6] + r[7]));
}

// kernel 1: codebook squared norms -> ws (numpy-pairwise-exact)
__global__ void e2_kernel(const float* __restrict__ cb, float* __restrict__ e2) {
    int i = blockIdx.x * blockDim.x + threadIdx.x;  // 0..8191
    e2[i] = np_sumsq_strided(cb + (size_t)i * ND, 1);
}

__global__ __launch_bounds__(256, 2) void rvq_kernel(
    const float* __restrict__ emb, const float* __restrict__ cbs,
    const float* __restrict__ e2ws, float* __restrict__ out)
{
    __shared__ float res[ND * TTILE];       // residual, [d][t]
    __shared__ float eb[DCHUNK * EBS];      // codebook sub-tile, [dd][k_local]
    __shared__ float e2l[KCHUNK];
    __shared__ float r2[TTILE];
    __shared__ int   idx_lds[TTILE];

    const int tid = threadIdx.x;
    const int bidx = blockIdx.x;
    const int b  = bidx >> 7;               // 128 token-tiles per batch
    const int t0 = (bidx & 127) * TTILE;
    const int tx = tid & 31;                // code group (8 codes)
    const int ty = tid >> 5;                // token group (8 tokens)

    const float* x = emb + (size_t)b * ND * NT + t0;

    // ---- load residual tile (x) into LDS, [d][t] ----
    {
        int d = tid >> 1, toff = (tid & 1) * 32;
        #pragma unroll
        for (int j = 0; j < 8; ++j) {
            float4 v = *(const float4*)(x + d * NT + toff + j * 4);
            *(float4*)&res[d * TTILE + toff + j * 4] = v;
        }
    }
    __syncthreads();
    // ---- initial r2 per token (numpy-pairwise-exact) ----
    if (tid < TTILE) r2[tid] = np_sumsq_strided(&res[tid], TTILE);
    __syncthreads();

    float* out_idx = out;                        // NQ*NB*NT floats (indices as float)
    float* out_qt  = out + (size_t)NQ * NB * NT; // NB*ND*NT floats

    for (int q = 0; q < NQ; ++q) {
        const float* cb = cbs + (size_t)q * NK * ND;
        float best_d[8]; int best_i[8];
        #pragma unroll
        for (int m = 0; m < 8; ++m) { best_d[m] = FLT_MAX; best_i[m] = 0; }

        for (int kc = 0; kc < NK / KCHUNK; ++kc) {
            float acc[8][8];
            #pragma unroll
            for (int m = 0; m < 8; ++m)
                #pragma unroll
                for (int n = 0; n < 8; ++n) acc[m][n] = 0.f;

            for (int ds = 0; ds < ND / DCHUNK; ++ds) {
                __syncthreads();   // protect eb/e2l readers of previous stage
                if (ds == 0) e2l[tid] = e2ws[q * NK + kc * KCHUNK + tid];
                // stage codebook sub-tile: codes [kc*256,+256), dims [ds*32,+32), transposed
                #pragma unroll
                for (int j = 0; j < 8; ++j) {
                    int li = j * 256 + tid;
                    int kl = li >> 3, f = li & 7;
                    float4 v = *(const float4*)(cb + (size_t)(kc * KCHUNK + kl) * ND + ds * DCHUNK + f * 4);
                    eb[(f * 4 + 0) * EBS + kl] = v.x;
                    eb[(f * 4 + 1) * EBS + kl] = v.y;
                    eb[(f * 4 + 2) * EBS + kl] = v.z;
                    eb[(f * 4 + 3) * EBS + kl] = v.w;
                }
                __syncthreads();
                // 8x8 register-tile microkernel; each acc[m][n] is a single
                // sequential fmaf chain over d=0..127 in order (BLAS-identical).
                #pragma unroll 8
                for (int dd = 0; dd < DCHUNK; ++dd) {
                    int d = ds * DCHUNK + dd;
                    float4 r0 = *(const float4*)&res[d * TTILE + ty * 8];
                    float4 r1 = *(const float4*)&res[d * TTILE + ty * 8 + 4];
                    float4 e0 = *(const float4*)&eb[dd * EBS + tx * 8];
                    float4 e1 = *(const float4*)&eb[dd * EBS + tx * 8 + 4];
                    float rv[8] = {r0.x, r0.y, r0.z, r0.w, r1.x, r1.y, r1.z, r1.w};
                    float ev[8] = {e0.x, e0.y, e0.z, e0.w, e1.x, e1.y, e1.z, e1.w};
                    #pragma unroll
                    for (int m = 0; m < 8; ++m)
                        #pragma unroll
                        for (int n = 0; n < 8; ++n)
                            acc[m][n] = fmaf(rv[m], ev[n], acc[m][n]);
                }
            }
            // argmin update; dist assembled exactly like numpy: (A - 2*B) + C,
            // contraction off. k ascending + strict < = first occurrence.
            #pragma unroll
            for (int m = 0; m < 8; ++m) {
                float rr = r2[ty * 8 + m];
                #pragma unroll
                for (int n = 0; n < 8; ++n) {
                    float dist;
                    {
                    #pragma clang fp contract(off)
                        dist = (rr - 2.0f * acc[m][n]) + e2l[tx * 8 + n];
                    }
                    int gk = kc * KCHUNK + tx * 8 + n;
                    if (dist < best_d[m]) { best_d[m] = dist; best_i[m] = gk; }
                }
            }
        }
        // cross-lane argmin reduce over tx (32 lanes), tie -> smaller index
        #pragma unroll
        for (int off = 16; off >= 1; off >>= 1) {
            #pragma unroll
            for (int m = 0; m < 8; ++m) {
                float od = __shfl_xor(best_d[m], off, 32);
                int   oi = __shfl_xor(best_i[m], off, 32);
                if (od < best_d[m] || (od == best_d[m] && oi < best_i[m])) {
                    best_d[m] = od; best_i[m] = oi;
                }
            }
        }
        if (tx == 0) {
            #pragma unroll
            for (int m = 0; m < 8; ++m) idx_lds[ty * 8 + m] = best_i[m];
        }
        __syncthreads();
        if (tid < TTILE)
            out_idx[(size_t)q * NB * NT + (size_t)b * NT + t0 + tid] = (float)idx_lds[tid];
        // residual -= codebook[idx]
        {
            int t = tid & 63, grp = tid >> 6;
            int ki = idx_lds[t];
            const float* erow = cb + (size_t)ki * ND + grp * 32;
            #pragma unroll
            for (int j = 0; j < 32; ++j) {
                res[(grp * 32 + j) * TTILE + t] = res[(grp * 32 + j) * TTILE + t] - erow[j];
            }
        }
        __syncthreads();
        // recompute r2 (numpy-pairwise-exact, matches ref's fresh sum each step)
        if (tid < TTILE) r2[tid] = np_sumsq_strided(&res[tid], TTILE);
        __syncthreads();
    }

    // quantized output = x - final residual, layout [B][D][T]
    {
        int d = tid >> 1, toff = (tid & 1) * 32;
        float* o = out_qt + (size_t)b * ND * NT + t0;
        #pragma unroll
        for (int j = 0; j < 8; ++j) {
            float4 xv = *(const float4*)(x + d * NT + toff + j * 4);
            float4 rv = *(const float4*)&res[d * TTILE + toff + j * 4];
            float4 ov = {xv.x - rv.x, xv.y - rv.y, xv.z - rv.z, xv.w - rv.w};
            *(float4*)(o + d * NT + toff + j * 4) = ov;
        }
    }
}

extern "C" void kernel_launch(void* const* d_in, const int* in_sizes, int n_in,
                              void* d_out, int out_size, void* d_ws, size_t ws_size,
                              hipStream_t stream) {
    const float* emb = (const float*)d_in[0];   // [8,128,8192]
    const float* cbs = (const float*)d_in[1];   // [8,1024,128]
    float* out = (float*)d_out;
    float* e2ws = (float*)d_ws;                 // 8192 floats

    e2_kernel<<<NQ * NK / 256, 256, 0, stream>>>(cbs, e2ws);
    rvq_kernel<<<NB * NT / TTILE, 256, 0, stream>>>(emb, cbs, e2ws, out);
}

// Round 9
// 1209.486 us; speedup vs baseline: 1.5077x; 1.5077x over previous
//
#include <hip/hip_runtime.h>
#include <float.h>

#define NQ 8
#define NB 8
#define ND 128
#define NT 8192
#define NK 1024
#define TTILE 64
#define ESTR 136          // eb row stride in halves (128 + 8 pad -> even bank spread)
#define TAU 2e-3f         // refine margin; approx-vs-numpy err bound ~1e-4 << TAU/2

typedef _Float16 half8 __attribute__((ext_vector_type(8)));
typedef float f32x4 __attribute__((ext_vector_type(4)));

// numpy pairwise-8 sum of squares over 128 values (np.sum(a*a, -1), n=128):
// products rounded individually, 8 stride-8 accumulators, fixed combine tree.
__device__ __forceinline__ float np_sumsq_strided(const float* a, int stride) {
#pragma clang fp contract(off)
    float r[8];
    #pragma unroll
    for (int j = 0; j < 8; ++j) { float v = a[j * stride]; r[j] = v * v; }
    #pragma unroll
    for (int i = 1; i < 16; ++i) {
        #pragma unroll
        for (int j = 0; j < 8; ++j) {
            float v = a[(i * 8 + j) * stride];
            r[j] = r[j] + v * v;
        }
    }
    return ((r[0] + r[1]) + (r[2] + r[3])) + ((r[4] + r[5]) + (r[6] + r[7]));
}

// kernel 1: codebook squared norms -> ws (numpy-pairwise-exact)
__global__ void e2_kernel(const float* __restrict__ cb, float* __restrict__ e2) {
    int i = blockIdx.x * blockDim.x + threadIdx.x;  // 0..8191
    e2[i] = np_sumsq_strided(cb + (size_t)i * ND, 1);
}

__global__ __launch_bounds__(256, 2) void rvq_kernel(
    const float* __restrict__ emb, const float* __restrict__ cbs,
    const float* __restrict__ e2ws, float* __restrict__ out)
{
    __shared__ float res[ND * TTILE];        // residual, [d][t]  (np-bit-exact fp32)
    __shared__ _Float16 ebh[64 * ESTR];      // codebook fp16 hi plane, [row][d]
    __shared__ _Float16 ebl[64 * ESTR];      // codebook fp16 lo plane
    __shared__ float e2q[NK];                // np-bit e2 for this q
    __shared__ float mb1[2][TTILE], mb2[2][TTILE];
    __shared__ int   mi1[2][TTILE];
    __shared__ int   idx_lds[TTILE];
    __shared__ unsigned long long flagmask;
    __shared__ float wbd[4]; __shared__ int wbi[4];

    const int tid  = threadIdx.x;
    const int lane = tid & 63;
    const int wv   = tid >> 6;
    const int tg   = wv >> 1;     // token group: 32 tokens
    const int ch   = wv & 1;      // code half: 512 codes
    const int c16  = lane & 15;
    const int g4   = lane >> 4;

    const int bidx = blockIdx.x;
    const int b  = bidx >> 7;
    const int t0 = (bidx & 127) * TTILE;
    const float* x = emb + (size_t)b * ND * NT + t0;

    // ---- load residual tile (x) into LDS, [d][t] ----
    {
        int d = tid >> 1, toff = (tid & 1) * 32;
        #pragma unroll
        for (int j = 0; j < 8; ++j)
            *(float4*)&res[d * TTILE + toff + j * 4] = *(const float4*)(x + d * NT + toff + j * 4);
    }
    __syncthreads();

    float* out_idx = out;                         // NQ*NB*NT floats (indices as float)
    float* out_qt  = out + (size_t)NQ * NB * NT;  // NB*ND*NT floats

    for (int q = 0; q < NQ; ++q) {
        const float* cb = cbs + (size_t)q * NK * ND;

        // ---- A-fragments (fp16 split of residual) into registers, once per q ----
        half8 aH[2][4], aL[2][4];
        #pragma unroll
        for (int mt = 0; mt < 2; ++mt) {
            int tok = tg * 32 + mt * 16 + c16;
            #pragma unroll
            for (int kk = 0; kk < 4; ++kk) {
                int k0 = kk * 32 + g4 * 8;
                half8 hh, hl;
                #pragma unroll
                for (int j = 0; j < 8; ++j) {
                    float v = res[(k0 + j) * TTILE + tok];
                    _Float16 h = (_Float16)v;
                    hh[j] = h;
                    hl[j] = (_Float16)(v - (float)h);
                }
                aH[mt][kk] = hh; aL[mt][kk] = hl;
            }
        }
        // ---- e2 for this q into LDS (np bits) ----
        #pragma unroll
        for (int c = 0; c < 4; ++c) e2q[c * 256 + tid] = e2ws[q * NK + c * 256 + tid];

        // ---- per-lane top2 state: s = mt*4 + j ----
        float B1[8], B2[8]; int I1[8];
        #pragma unroll
        for (int s = 0; s < 8; ++s) { B1[s] = FLT_MAX; B2[s] = FLT_MAX; I1[s] = 0; }

        for (int r = 0; r < 16; ++r) {
            __syncthreads();   // prev-round eb readers done (also covers e2q/A vs prev q)
            // ---- stage 64 code rows (32 per half) as fp16 hi/lo planes ----
            {
                int row = tid >> 2, seg = tid & 3;
                int gcode = (row >> 5) * 512 + r * 32 + (row & 31);
                const float* gs = cb + (size_t)gcode * ND + seg * 32;
                _Float16* dh = &ebh[row * ESTR + seg * 32];
                _Float16* dl = &ebl[row * ESTR + seg * 32];
                #pragma unroll
                for (int u = 0; u < 4; ++u) {
                    float4 v0 = *(const float4*)(gs + u * 8);
                    float4 v1 = *(const float4*)(gs + u * 8 + 4);
                    float vv[8] = {v0.x, v0.y, v0.z, v0.w, v1.x, v1.y, v1.z, v1.w};
                    half8 hh, hl;
                    #pragma unroll
                    for (int j = 0; j < 8; ++j) {
                        _Float16 h = (_Float16)vv[j];
                        hh[j] = h;
                        hl[j] = (_Float16)(vv[j] - (float)h);
                    }
                    *(half8*)(dh + u * 8) = hh;
                    *(half8*)(dl + u * 8) = hl;
                }
            }
            __syncthreads();

            #pragma unroll
            for (int cblk = 0; cblk < 2; ++cblk) {
                int crow = ch * 32 + cblk * 16 + c16;
                half8 bH[4], bL[4];
                #pragma unroll
                for (int kk = 0; kk < 4; ++kk) {
                    bH[kk] = *(const half8*)&ebh[crow * ESTR + kk * 32 + g4 * 8];
                    bL[kk] = *(const half8*)&ebl[crow * ESTR + kk * 32 + g4 * 8];
                }
                int gk = ch * 512 + r * 32 + cblk * 16 + c16;
                float e2v = e2q[gk];

                f32x4 acc0 = {0.f, 0.f, 0.f, 0.f};
                f32x4 acc1 = {0.f, 0.f, 0.f, 0.f};
                #pragma unroll
                for (int s = 0; s < 4; ++s) {      // (sa = s>>1, sb = s&1)
                    #pragma unroll
                    for (int kk = 0; kk < 4; ++kk) {
                        half8 a0 = (s & 2) ? aL[0][kk] : aH[0][kk];
                        half8 a1 = (s & 2) ? aL[1][kk] : aH[1][kk];
                        half8 bb = (s & 1) ? bL[kk] : bH[kk];
                        acc0 = __builtin_amdgcn_mfma_f32_16x16x32_f16(a0, bb, acc0, 0, 0, 0);
                        acc1 = __builtin_amdgcn_mfma_f32_16x16x32_f16(a1, bb, acc1, 0, 0, 0);
                    }
                }
                // rank by (e2 - 2*dot); r2 is per-token-constant (argmin-invariant)
                #pragma unroll
                for (int j = 0; j < 4; ++j) {
                    float d0 = fmaf(-2.f, acc0[j], e2v);
                    if (d0 < B1[j])      { B2[j] = B1[j]; B1[j] = d0; I1[j] = gk; }
                    else if (d0 < B2[j]) { B2[j] = d0; }
                    float d1 = fmaf(-2.f, acc1[j], e2v);
                    if (d1 < B1[4 + j])      { B2[4 + j] = B1[4 + j]; B1[4 + j] = d1; I1[4 + j] = gk; }
                    else if (d1 < B2[4 + j]) { B2[4 + j] = d1; }
                }
            }
        }

        // ---- cross-lane top2 merge over the 16 code-lanes ----
        #pragma unroll
        for (int s = 0; s < 8; ++s) {
            #pragma unroll
            for (int off = 1; off < 16; off <<= 1) {
                float ob1 = __shfl_xor(B1[s], off, 16);
                float ob2 = __shfl_xor(B2[s], off, 16);
                int   oi  = __shfl_xor(I1[s], off, 16);
                if (ob1 < B1[s] || (ob1 == B1[s] && oi < I1[s])) {
                    B2[s] = fminf(B1[s], ob2); B1[s] = ob1; I1[s] = oi;
                } else {
                    B2[s] = fminf(ob1, B2[s]);
                }
            }
        }
        if (c16 == 0) {
            #pragma unroll
            for (int mt = 0; mt < 2; ++mt)
                #pragma unroll
                for (int j = 0; j < 4; ++j) {
                    int tl = tg * 32 + mt * 16 + g4 * 4 + j;
                    int s = mt * 4 + j;
                    mb1[ch][tl] = B1[s]; mb2[ch][tl] = B2[s]; mi1[ch][tl] = I1[s];
                }
        }
        __syncthreads();

        // ---- merge code-halves; flag near-ties ----
        if (tid < TTILE) {
            float b1 = mb1[0][tid], b2 = mb2[0][tid]; int i1 = mi1[0][tid];
            float c1 = mb1[1][tid], c2 = mb2[1][tid]; int j1 = mi1[1][tid];
            if (c1 < b1) { b2 = fminf(b1, c2); b1 = c1; i1 = j1; }   // tie -> ch0 (lower idx)
            else         { b2 = fminf(c1, b2); }
            idx_lds[tid] = i1;
            bool flag = (b2 - b1) < TAU;
            unsigned long long fm = __ballot(flag);
            if (tid == 0) flagmask = fm;
        }
        __syncthreads();

        // ---- exact (numpy-bit) refine for flagged tokens (rare) ----
        unsigned long long mask = flagmask;
        while (mask) {
            int t = __ffsll((long long)mask) - 1; mask &= mask - 1;
            float r2t = np_sumsq_strided(&res[t], TTILE);   // broadcast reads
            float bd = FLT_MAX; int bi = 0;
            #pragma unroll
            for (int c = 0; c < 4; ++c) {
                int k = tid + 256 * c;   // per-thread k ascending
                const float* er = cb + (size_t)k * ND;
                float s = 0.f;
                #pragma unroll 8
                for (int d = 0; d < ND; ++d)
                    s = fmaf(res[d * TTILE + t], er[d], s);   // BLAS/einsum-identical chain
                float dist;
                {
                #pragma clang fp contract(off)
                    dist = (r2t - 2.0f * s) + e2q[k];
                }
                if (dist < bd) { bd = dist; bi = k; }
            }
            #pragma unroll
            for (int off = 32; off >= 1; off >>= 1) {
                float od = __shfl_xor(bd, off);
                int   oi = __shfl_xor(bi, off);
                if (od < bd || (od == bd && oi < bi)) { bd = od; bi = oi; }
            }
            if (lane == 0) { wbd[wv] = bd; wbi[wv] = bi; }
            __syncthreads();
            if (tid == 0) {
                #pragma unroll
                for (int w = 1; w < 4; ++w)
                    if (wbd[w] < bd || (wbd[w] == bd && wbi[w] < bi)) { bd = wbd[w]; bi = wbi[w]; }
                idx_lds[t] = bi;
            }
            __syncthreads();
        }

        // ---- write indices; residual -= codebook[idx] (exact fp32) ----
        if (tid < TTILE)
            out_idx[(size_t)q * NB * NT + (size_t)b * NT + t0 + tid] = (float)idx_lds[tid];
        {
            int t = tid & 63, grp = tid >> 6;
            int ki = idx_lds[t];
            const float* erow = cb + (size_t)ki * ND + grp * 32;
            #pragma unroll
            for (int j = 0; j < 32; ++j)
                res[(grp * 32 + j) * TTILE + t] = res[(grp * 32 + j) * TTILE + t] - erow[j];
        }
        __syncthreads();
    }

    // ---- quantized output = x - final residual, layout [B][D][T] ----
    {
        int d = tid >> 1, toff = (tid & 1) * 32;
        float* o = out_qt + (size_t)b * ND * NT + t0;
        #pragma unroll
        for (int j = 0; j < 8; ++j) {
            float4 xv = *(const float4*)(x + d * NT + toff + j * 4);
            float4 rv = *(const float4*)&res[d * TTILE + toff + j * 4];
            float4 ov = {xv.x - rv.x, xv.y - rv.y, xv.z - rv.z, xv.w - rv.w};
            *(float4*)(o + d * NT + toff + j * 4) = ov;
        }
    }
}

extern "C" void kernel_launch(void* const* d_in, const int* in_sizes, int n_in,
                              void* d_out, int out_size, void* d_ws, size_t ws_size,
                              hipStream_t stream) {
    const float* emb = (const float*)d_in[0];   // [8,128,8192]
    const float* cbs = (const float*)d_in[1];   // [8,1024,128]
    float* out = (float*)d_out;
    float* e2ws = (float*)d_ws;                 // 8192 floats

    e2_kernel<<<NQ * NK / 256, 256, 0, stream>>>(cbs, e2ws);
    rvq_kernel<<<NB * NT / TTILE, 256, 0, stream>>>(emb, cbs, e2ws, out);
}

// Round 10
// 978.706 us; speedup vs baseline: 1.8633x; 1.2358x over previous
//
#include <hip/hip_runtime.h>
#include <float.h>

#define NQ 8
#define NB 8
#define ND 128
#define NT 8192
#define NK 1024
#define TTILE 64
#define ESTR 136                    // plane row stride in halves (128 + 8 pad)
#define PLANE_HALVES (64 * ESTR)    // 8704 halves = 17408 B per plane
#define TAU 2e-3f                   // refine margin; approx err ~1.5e-4 << TAU/2

typedef _Float16 half8 __attribute__((ext_vector_type(8)));
typedef float f32x4 __attribute__((ext_vector_type(4)));

// numpy pairwise-8 sum of squares over 128 values (np.sum(a*a, -1), n=128):
// products rounded individually, 8 stride-8 accumulators, fixed combine tree.
__device__ __forceinline__ float np_sumsq_strided(const float* a, int stride) {
#pragma clang fp contract(off)
    float r[8];
    #pragma unroll
    for (int j = 0; j < 8; ++j) { float v = a[j * stride]; r[j] = v * v; }
    #pragma unroll
    for (int i = 1; i < 16; ++i) {
        #pragma unroll
        for (int j = 0; j < 8; ++j) {
            float v = a[(i * 8 + j) * stride];
            r[j] = r[j] + v * v;
        }
    }
    return ((r[0] + r[1]) + (r[2] + r[3])) + ((r[4] + r[5]) + (r[6] + r[7]));
}

// kernel 1: codebook squared norms -> ws (numpy-pairwise-exact)
__global__ void e2_kernel(const float* __restrict__ cb, float* __restrict__ e2) {
    int i = blockIdx.x * blockDim.x + threadIdx.x;  // 0..8191
    e2[i] = np_sumsq_strided(cb + (size_t)i * ND, 1);
}

// kernel 2: codebooks -> fp16 hi/lo planes in ws, in per-(q,round) staged order.
// Plane block (q,r): [64 rows hi @ ESTR][64 rows lo @ ESTR]; staged row sr maps
// to code (sr>>5)*512 + r*32 + (sr&31)  (two 32-code chunks, one per code-half).
__global__ void prep_kernel(const float* __restrict__ cbs, _Float16* __restrict__ planes) {
    int qr = blockIdx.x;            // 0..127 = q*16 + r
    int q = qr >> 4, r = qr & 15;
    int tid = threadIdx.x;
    int sr = tid >> 2, seg = tid & 3;
    int gcode = (sr >> 5) * 512 + r * 32 + (sr & 31);
    const float* gs = cbs + ((size_t)q * NK + gcode) * ND + seg * 32;
    _Float16* dh = planes + (size_t)qr * 2 * PLANE_HALVES + sr * ESTR + seg * 32;
    _Float16* dl = dh + PLANE_HALVES;
    #pragma unroll
    for (int u = 0; u < 4; ++u) {
        float4 v0 = *(const float4*)(gs + u * 8);
        float4 v1 = *(const float4*)(gs + u * 8 + 4);
        float vv[8] = {v0.x, v0.y, v0.z, v0.w, v1.x, v1.y, v1.z, v1.w};
        half8 hh, hl;
        #pragma unroll
        for (int j = 0; j < 8; ++j) {
            _Float16 h = (_Float16)vv[j];
            hh[j] = h;
            hl[j] = (_Float16)(vv[j] - (float)h);
        }
        *(half8*)(dh + u * 8) = hh;
        *(half8*)(dl + u * 8) = hl;
    }
}

__global__ __launch_bounds__(256, 2) void rvq_kernel(
    const float* __restrict__ emb, const float* __restrict__ cbs,
    const float* __restrict__ e2ws, const _Float16* __restrict__ planes,
    float* __restrict__ out)
{
    __shared__ float res[ND * TTILE];          // residual, [d][t] (np-bit fp32)
    __shared__ _Float16 eb[2 * PLANE_HALVES];  // staged hi plane + lo plane
    __shared__ float e2q[NK];
    __shared__ float mb1[2][TTILE], mb2[2][TTILE];
    __shared__ int   mi1[2][TTILE];
    __shared__ int   idx_lds[TTILE];
    __shared__ unsigned long long flagmask;
    __shared__ float wbd[4]; __shared__ int wbi[4];

    const int tid  = threadIdx.x;
    const int lane = tid & 63;
    const int wv   = tid >> 6;
    const int tg   = wv >> 1;     // token group: 32 tokens
    const int ch   = wv & 1;      // code half: 512 codes
    const int c16  = lane & 15;
    const int g4   = lane >> 4;

    const int bidx = blockIdx.x;
    const int b  = bidx >> 7;
    const int t0 = (bidx & 127) * TTILE;
    const float* x = emb + (size_t)b * ND * NT + t0;

    // ---- load residual tile (x) into LDS, [d][t] ----
    {
        int d = tid >> 1, toff = (tid & 1) * 32;
        #pragma unroll
        for (int j = 0; j < 8; ++j)
            *(float4*)&res[d * TTILE + toff + j * 4] = *(const float4*)(x + d * NT + toff + j * 4);
    }
    __syncthreads();

    float* out_idx = out;                         // NQ*NB*NT floats (indices as float)
    float* out_qt  = out + (size_t)NQ * NB * NT;  // NB*ND*NT floats

    for (int q = 0; q < NQ; ++q) {
        const float* cb = cbs + (size_t)q * NK * ND;

        // ---- A-fragments (fp16 split of residual) into registers, once per q ----
        half8 aH[2][4], aL[2][4];
        #pragma unroll
        for (int mt = 0; mt < 2; ++mt) {
            int tok = tg * 32 + mt * 16 + c16;
            #pragma unroll
            for (int kk = 0; kk < 4; ++kk) {
                int k0 = kk * 32 + g4 * 8;
                half8 hh, hl;
                #pragma unroll
                for (int j = 0; j < 8; ++j) {
                    float v = res[(k0 + j) * TTILE + tok];
                    _Float16 h = (_Float16)v;
                    hh[j] = h;
                    hl[j] = (_Float16)(v - (float)h);
                }
                aH[mt][kk] = hh; aL[mt][kk] = hl;
            }
        }
        // ---- e2 for this q into LDS (np bits) ----
        #pragma unroll
        for (int c = 0; c < 4; ++c) e2q[c * 256 + tid] = e2ws[q * NK + c * 256 + tid];

        // ---- per-lane top2 state: s = mt*4 + j ----
        float B1[8], B2[8]; int I1[8];
        #pragma unroll
        for (int s = 0; s < 8; ++s) { B1[s] = FLT_MAX; B2[s] = FLT_MAX; I1[s] = 0; }

        for (int r = 0; r < 16; ++r) {
            __syncthreads();   // prev-round eb readers done; e2q/A vs prev q done
            // ---- async-stage both planes: contiguous 34 KiB, 34 x 1KiB wave-chunks ----
            {
                const char* src = (const char*)(planes + (size_t)(q * 16 + r) * 2 * PLANE_HALVES);
                for (int c = wv; c < 34; c += 4) {
                    const char* g = src + c * 1024 + (lane << 4);
                    char* l = (char*)eb + c * 1024;  // wave-uniform base; HW adds lane*16
                    __builtin_amdgcn_global_load_lds(
                        (const __attribute__((address_space(1))) unsigned int*)g,
                        (__attribute__((address_space(3))) unsigned int*)l, 16, 0, 0);
                }
            }
            __syncthreads();   // barrier drain waits vmcnt(0) -> eb ready

            #pragma unroll
            for (int cblk = 0; cblk < 2; ++cblk) {
                int crow = ch * 32 + cblk * 16 + c16;
                half8 bH[4], bL[4];
                #pragma unroll
                for (int kk = 0; kk < 4; ++kk) {
                    bH[kk] = *(const half8*)&eb[crow * ESTR + kk * 32 + g4 * 8];
                    bL[kk] = *(const half8*)&eb[PLANE_HALVES + crow * ESTR + kk * 32 + g4 * 8];
                }
                int gk = ch * 512 + r * 32 + cblk * 16 + c16;
                float e2v = e2q[gk];

                f32x4 acc0 = {0.f, 0.f, 0.f, 0.f};
                f32x4 acc1 = {0.f, 0.f, 0.f, 0.f};
                #pragma unroll
                for (int kk = 0; kk < 4; ++kk) {   // hi*hi
                    acc0 = __builtin_amdgcn_mfma_f32_16x16x32_f16(aH[0][kk], bH[kk], acc0, 0, 0, 0);
                    acc1 = __builtin_amdgcn_mfma_f32_16x16x32_f16(aH[1][kk], bH[kk], acc1, 0, 0, 0);
                }
                #pragma unroll
                for (int kk = 0; kk < 4; ++kk) {   // hi*lo
                    acc0 = __builtin_amdgcn_mfma_f32_16x16x32_f16(aH[0][kk], bL[kk], acc0, 0, 0, 0);
                    acc1 = __builtin_amdgcn_mfma_f32_16x16x32_f16(aH[1][kk], bL[kk], acc1, 0, 0, 0);
                }
                #pragma unroll
                for (int kk = 0; kk < 4; ++kk) {   // lo*hi  (lo*lo dropped: ~2e-5 << TAU)
                    acc0 = __builtin_amdgcn_mfma_f32_16x16x32_f16(aL[0][kk], bH[kk], acc0, 0, 0, 0);
                    acc1 = __builtin_amdgcn_mfma_f32_16x16x32_f16(aL[1][kk], bH[kk], acc1, 0, 0, 0);
                }
                // rank by (e2 - 2*dot); r2 is per-token-constant (argmin-invariant)
                #pragma unroll
                for (int j = 0; j < 4; ++j) {
                    float d0 = fmaf(-2.f, acc0[j], e2v);
                    if (d0 < B1[j])      { B2[j] = B1[j]; B1[j] = d0; I1[j] = gk; }
                    else if (d0 < B2[j]) { B2[j] = d0; }
                    float d1 = fmaf(-2.f, acc1[j], e2v);
                    if (d1 < B1[4 + j])      { B2[4 + j] = B1[4 + j]; B1[4 + j] = d1; I1[4 + j] = gk; }
                    else if (d1 < B2[4 + j]) { B2[4 + j] = d1; }
                }
            }
        }

        // ---- cross-lane top2 merge over the 16 code-lanes ----
        #pragma unroll
        for (int s = 0; s < 8; ++s) {
            #pragma unroll
            for (int off = 1; off < 16; off <<= 1) {
                float ob1 = __shfl_xor(B1[s], off, 16);
                float ob2 = __shfl_xor(B2[s], off, 16);
                int   oi  = __shfl_xor(I1[s], off, 16);
                if (ob1 < B1[s] || (ob1 == B1[s] && oi < I1[s])) {
                    B2[s] = fminf(B1[s], ob2); B1[s] = ob1; I1[s] = oi;
                } else {
                    B2[s] = fminf(ob1, B2[s]);
                }
            }
        }
        if (c16 == 0) {
            #pragma unroll
            for (int mt = 0; mt < 2; ++mt)
                #pragma unroll
                for (int j = 0; j < 4; ++j) {
                    int tl = tg * 32 + mt * 16 + g4 * 4 + j;
                    int s = mt * 4 + j;
                    mb1[ch][tl] = B1[s]; mb2[ch][tl] = B2[s]; mi1[ch][tl] = I1[s];
                }
        }
        __syncthreads();

        // ---- merge code-halves; flag near-ties ----
        if (tid < TTILE) {
            float b1 = mb1[0][tid], b2 = mb2[0][tid]; int i1 = mi1[0][tid];
            float c1 = mb1[1][tid], c2 = mb2[1][tid]; int j1 = mi1[1][tid];
            if (c1 < b1) { b2 = fminf(b1, c2); b1 = c1; i1 = j1; }   // tie -> ch0 (lower idx)
            else         { b2 = fminf(c1, b2); }
            idx_lds[tid] = i1;
            bool flag = (b2 - b1) < TAU;
            unsigned long long fm = __ballot(flag);
            if (tid == 0) flagmask = fm;
        }
        __syncthreads();

        // ---- exact (numpy-bit) refine for flagged tokens (rare) ----
        unsigned long long mask = flagmask;
        while (mask) {
            int t = __ffsll((long long)mask) - 1; mask &= mask - 1;
            float r2t = np_sumsq_strided(&res[t], TTILE);   // broadcast reads
            float bd = FLT_MAX; int bi = 0;
            #pragma unroll
            for (int c = 0; c < 4; ++c) {
                int k = tid + 256 * c;   // per-thread k ascending
                const float* er = cb + (size_t)k * ND;
                float s = 0.f;
                #pragma unroll 8
                for (int d = 0; d < ND; ++d)
                    s = fmaf(res[d * TTILE + t], er[d], s);   // BLAS/einsum-identical chain
                float dist;
                {
                #pragma clang fp contract(off)
                    dist = (r2t - 2.0f * s) + e2q[k];
                }
                if (dist < bd) { bd = dist; bi = k; }
            }
            #pragma unroll
            for (int off = 32; off >= 1; off >>= 1) {
                float od = __shfl_xor(bd, off);
                int   oi = __shfl_xor(bi, off);
                if (od < bd || (od == bd && oi < bi)) { bd = od; bi = oi; }
            }
            if (lane == 0) { wbd[wv] = bd; wbi[wv] = bi; }
            __syncthreads();
            if (tid == 0) {
                #pragma unroll
                for (int w = 1; w < 4; ++w)
                    if (wbd[w] < bd || (wbd[w] == bd && wbi[w] < bi)) { bd = wbd[w]; bi = wbi[w]; }
                idx_lds[t] = bi;
            }
            __syncthreads();
        }

        // ---- write indices; residual -= codebook[idx] (exact fp32) ----
        if (tid < TTILE)
            out_idx[(size_t)q * NB * NT + (size_t)b * NT + t0 + tid] = (float)idx_lds[tid];
        {
            int t = tid & 63, grp = tid >> 6;
            int ki = idx_lds[t];
            const float* erow = cb + (size_t)ki * ND + grp * 32;
            #pragma unroll
            for (int j = 0; j < 32; ++j)
                res[(grp * 32 + j) * TTILE + t] = res[(grp * 32 + j) * TTILE + t] - erow[j];
        }
        __syncthreads();
    }

    // ---- quantized output = x - final residual, layout [B][D][T] ----
    {
        int d = tid >> 1, toff = (tid & 1) * 32;
        float* o = out_qt + (size_t)b * ND * NT + t0;
        #pragma unroll
        for (int j = 0; j < 8; ++j) {
            float4 xv = *(const float4*)(x + d * NT + toff + j * 4);
            float4 rv = *(const float4*)&res[d * TTILE + toff + j * 4];
            float4 ov = {xv.x - rv.x, xv.y - rv.y, xv.z - rv.z, xv.w - rv.w};
            *(float4*)(o + d * NT + toff + j * 4) = ov;
        }
    }
}

extern "C" void kernel_launch(void* const* d_in, const int* in_sizes, int n_in,
                              void* d_out, int out_size, void* d_ws, size_t ws_size,
                              hipStream_t stream) {
    const float* emb = (const float*)d_in[0];   // [8,128,8192]
    const float* cbs = (const float*)d_in[1];   // [8,1024,128]
    float* out = (float*)d_out;
    float* e2ws = (float*)d_ws;                                 // 8192 floats
    _Float16* planes = (_Float16*)((char*)d_ws + 32768);        // ~4.36 MB staged planes

    e2_kernel<<<NQ * NK / 256, 256, 0, stream>>>(cbs, e2ws);
    prep_kernel<<<NQ * 16, 256, 0, stream>>>(cbs, planes);
    rvq_kernel<<<NB * NT / TTILE, 256, 0, stream>>>(emb, cbs, e2ws, planes, out);
}